// Round 1
// baseline (266.415 us; speedup 1.0000x reference)
//
#include <hip/hip_runtime.h>

#define D 8

// Pass 1: claim each (src,dst) tile with atomicMax(edge_id+1) in the tile's
// first int slot. d_out was memset to 0, so untouched tiles read as 0.0f and
// any edge id (>=1) beats the initial 0. Max edge id == last edge == numpy
// last-write-wins semantics for duplicate pairs.
__global__ void sheaf_claim_kernel(const int* __restrict__ src,
                                   const int* __restrict__ dst,
                                   int* __restrict__ out_i, int n, int e) {
    int k = blockIdx.x * blockDim.x + threadIdx.x;
    if (k >= e) return;
    long long pair = (long long)src[k] * (long long)n + (long long)dst[k];
    atomicMax(&out_i[pair * 64], k + 1);
}

// Pass 2: one wave (64 lanes) per edge; lane o computes output element o of
// the 8x8 tile. The wave issues ONE load of the claim slot (all 64 lanes read
// the same address -> broadcast) strictly before any store, so the winning
// edge's own write of element 0 cannot confuse its own claim check.
__global__ void sheaf_scatter_kernel(const float* __restrict__ x,
                                     const int* __restrict__ src,
                                     const int* __restrict__ dst,
                                     const float* __restrict__ W,
                                     float* __restrict__ out, int n, int e) {
    int gid = blockIdx.x * blockDim.x + threadIdx.x;
    int k = gid >> 6;   // edge index
    int o = gid & 63;   // output element within the 8x8 tile (r*8+c)
    if (k >= e) return;

    int s = src[k];
    int d = dst[k];
    long long base = ((long long)s * (long long)n + (long long)d) * 64;

    // Claim check: only the winning (last) duplicate edge writes.
    int claim = __float_as_int(out[base]);
    if (claim != k + 1) return;

    const float* xs = x + s * D;
    const float* xd = x + d * D;
    const float* w  = W + o * D;

    float acc = 0.0f;
#pragma unroll
    for (int i = 0; i < D; ++i) {
        acc += fabsf(xs[i] - xd[i]) * w[i];
    }
    out[base + o] = acc;
}

extern "C" void kernel_launch(void* const* d_in, const int* in_sizes, int n_in,
                              void* d_out, int out_size, void* d_ws, size_t ws_size,
                              hipStream_t stream) {
    const float* x   = (const float*)d_in[0];
    const int*   ei  = (const int*)d_in[1];   // [2, e] flat: src first, dst second
    const float* W   = (const float*)d_in[2]; // [64, 8] row-major

    int n = in_sizes[0] / D;       // 1024
    int e = in_sizes[1] / 2;       // 32768
    const int* src = ei;
    const int* dst = ei + e;

    float* out = (float*)d_out;

    // Zero the 256 MiB output (write-BW bound; the dominant cost).
    hipMemsetAsync(out, 0, (size_t)out_size * sizeof(float), stream);

    // Pass 1: claim tiles (last edge wins).
    {
        int threads = 256;
        int blocks = (e + threads - 1) / threads;
        sheaf_claim_kernel<<<blocks, threads, 0, stream>>>(src, dst, (int*)out, n, e);
    }

    // Pass 2: compute and write 8x8 tiles, one wave per edge.
    {
        int threads = 256;
        long long total = (long long)e * 64;
        int blocks = (int)((total + threads - 1) / threads);
        sheaf_scatter_kernel<<<blocks, threads, 0, stream>>>(x, src, dst, W, out, n, e);
    }
}

// Round 2
// 259.681 us; speedup vs baseline: 1.0259x; 1.0259x over previous
//
#include <hip/hip_runtime.h>

#define D 8

// ---------- Plan A: claim table in d_ws, single-pass output ----------

__global__ void zero_ws_kernel(int* __restrict__ ws, int ntiles) {
    int i = blockIdx.x * blockDim.x + threadIdx.x;
    if (i < ntiles) ws[i] = 0;
}

__global__ void claim_ws_kernel(const int* __restrict__ src,
                                const int* __restrict__ dst,
                                int* __restrict__ ws, int n, int e) {
    int k = blockIdx.x * blockDim.x + threadIdx.x;
    if (k >= e) return;
    atomicMax(&ws[src[k] * n + dst[k]], k + 1);  // last edge wins (numpy semantics)
}

// One float4 (4 output elems) per thread; 16 threads cover one 8x8 tile.
// Wave = 4 consecutive tiles = 1 KiB contiguous stores.
__global__ void fused_out_kernel(const float* __restrict__ x,
                                 const int* __restrict__ src,
                                 const int* __restrict__ dst,
                                 const float* __restrict__ W,
                                 const int* __restrict__ ws,
                                 float4* __restrict__ out4,
                                 int ntiles) {
    int gid = blockIdx.x * blockDim.x + threadIdx.x;
    int tile = gid >> 4;
    int t = gid & 15;
    if (tile >= ntiles) return;

    int claim = ws[tile];
    if (claim == 0) {
        out4[gid] = make_float4(0.f, 0.f, 0.f, 0.f);
        return;
    }
    int k = claim - 1;
    int s = src[k], d = dst[k];
    const float* xs = x + s * D;
    const float* xd = x + d * D;

    float diff[D];
#pragma unroll
    for (int i = 0; i < D; ++i) diff[i] = fabsf(xs[i] - xd[i]);

    float4 r;
    float acc[4];
#pragma unroll
    for (int j = 0; j < 4; ++j) {
        int o = t * 4 + j;
        const float* w = W + o * D;
        float a = 0.f;
#pragma unroll
        for (int i = 0; i < D; ++i) a += diff[i] * w[i];
        acc[j] = a;
    }
    r.x = acc[0]; r.y = acc[1]; r.z = acc[2]; r.w = acc[3];
    out4[gid] = r;
}

// ---------- Plan B fallback (ws too small): claim slot lives in d_out ----------

__global__ void zero_out_kernel(float4* __restrict__ out4, int n4) {
    int i = blockIdx.x * blockDim.x + threadIdx.x;
    if (i < n4) out4[i] = make_float4(0.f, 0.f, 0.f, 0.f);
}

__global__ void claim_out_kernel(const int* __restrict__ src,
                                 const int* __restrict__ dst,
                                 int* __restrict__ out_i, int n, int e) {
    int k = blockIdx.x * blockDim.x + threadIdx.x;
    if (k >= e) return;
    long long pair = (long long)src[k] * n + dst[k];
    atomicMax(&out_i[pair * 64], k + 1);
}

__global__ void scatter_out_kernel(const float* __restrict__ x,
                                   const int* __restrict__ src,
                                   const int* __restrict__ dst,
                                   const float* __restrict__ W,
                                   float* __restrict__ out, int n, int e) {
    int gid = blockIdx.x * blockDim.x + threadIdx.x;
    int k = gid >> 6;
    int o = gid & 63;
    if (k >= e) return;
    int s = src[k], d = dst[k];
    long long base = ((long long)s * n + d) * 64;
    int claim = __float_as_int(out[base]);
    if (claim != k + 1) return;
    const float* xs = x + s * D;
    const float* xd = x + d * D;
    const float* w = W + o * D;
    float a = 0.f;
#pragma unroll
    for (int i = 0; i < D; ++i) a += fabsf(xs[i] - xd[i]) * w[i];
    out[base + o] = a;
}

extern "C" void kernel_launch(void* const* d_in, const int* in_sizes, int n_in,
                              void* d_out, int out_size, void* d_ws, size_t ws_size,
                              hipStream_t stream) {
    const float* x  = (const float*)d_in[0];
    const int*   ei = (const int*)d_in[1];   // [2, e]: src row then dst row
    const float* W  = (const float*)d_in[2]; // [64, 8] row-major

    int n = in_sizes[0] / D;   // 1024
    int e = in_sizes[1] / 2;   // 32768
    const int* src = ei;
    const int* dst = ei + e;

    int ntiles = out_size / 64;            // n*n
    int n4 = out_size / 4;                 // float4 count

    if (ws_size >= (size_t)ntiles * sizeof(int)) {
        int* ws = (int*)d_ws;
        {
            int threads = 256, blocks = (ntiles + threads - 1) / threads;
            zero_ws_kernel<<<blocks, threads, 0, stream>>>(ws, ntiles);
        }
        {
            int threads = 256, blocks = (e + threads - 1) / threads;
            claim_ws_kernel<<<blocks, threads, 0, stream>>>(src, dst, ws, n, e);
        }
        {
            int threads = 256;
            long long total = (long long)ntiles * 16;
            int blocks = (int)((total + threads - 1) / threads);
            fused_out_kernel<<<blocks, threads, 0, stream>>>(
                x, src, dst, W, ws, (float4*)d_out, ntiles);
        }
    } else {
        {
            int threads = 256, blocks = (n4 + threads - 1) / threads;
            zero_out_kernel<<<blocks, threads, 0, stream>>>((float4*)d_out, n4);
        }
        {
            int threads = 256, blocks = (e + threads - 1) / threads;
            claim_out_kernel<<<blocks, threads, 0, stream>>>(src, dst, (int*)d_out, n, e);
        }
        {
            int threads = 256;
            long long total = (long long)e * 64;
            int blocks = (int)((total + threads - 1) / threads);
            scatter_out_kernel<<<blocks, threads, 0, stream>>>(
                x, src, dst, W, (float*)d_out, n, e);
        }
    }
}